// Round 1
// baseline (899.721 us; speedup 1.0000x reference)
//
#include <hip/hip_runtime.h>
#include <hip/hip_bf16.h>
#include <stdint.h>

// ---------------------------------------------------------------------------
// HeteroTextGCN round 5:
//  - gather: combined 3-relation CSR (per-edge weight select), cooperative
//    64-wide edge-index load + __shfl broadcast (no dependent index loads),
//    dwordx2 paired-edge loads (2 edges / instruction, 8 edges in flight)
//  - hist: 8 per-XCD counter copies (unchanged)
//  - GEMMs: 3 relations merged into one dispatch (unchanged)
// ---------------------------------------------------------------------------

typedef __attribute__((ext_vector_type(8))) short bf16x8;
typedef __attribute__((ext_vector_type(4))) float f32x4;
typedef unsigned short u16;

#define SCAN_T 256
#define SCAN_E 8
#define SCAN_BLK (SCAN_T * SCAN_E)

// --- degree histograms into 8 per-XCD copies -------------------------------
__global__ __launch_bounds__(256)
void hist_kernel(const int* __restrict__ src, const int* __restrict__ dst,
                 int* __restrict__ cnt_out8, int* __restrict__ cnt_in8,
                 int E, int N) {
    int e = blockIdx.x * blockDim.x + threadIdx.x;
    int r = blockIdx.y;
    if (e >= E) return;
    int copy = blockIdx.x & 7;
    size_t base = ((size_t)copy * 3 + r) * N;
    atomicAdd(cnt_out8 + base + src[(size_t)r * E + e], 1);
    atomicAdd(cnt_in8  + base + dst[(size_t)r * E + e], 1);
}

// --- reduce 8 copies + rsqrt scales + combined (all-relation) in-degree ----
__global__ __launch_bounds__(256)
void reduce_scales_kernel(const int* __restrict__ cnt_out8, const int* __restrict__ cnt_in8,
                          float* __restrict__ s_out, float* __restrict__ s_in,
                          int* __restrict__ cnt_all, int N) {
    int n = blockIdx.x * blockDim.x + threadIdx.x;
    if (n >= N) return;
    int tot = 0;
#pragma unroll
    for (int r = 0; r < 3; r++) {
        int co = 0, ci = 0;
#pragma unroll
        for (int c = 0; c < 8; c++) {
            co += cnt_out8[((size_t)c * 3 + r) * N + n];
            ci += cnt_in8[((size_t)c * 3 + r) * N + n];
        }
        s_out[(size_t)r * N + n] = rsqrtf(fmaxf((float)co, 1.0f));
        s_in[(size_t)r * N + n]  = rsqrtf(fmaxf((float)ci, 1.0f));
        tot += ci;
    }
    cnt_all[n] = tot;
}

// --- exclusive scan over combined in-degree (single row) -------------------
__global__ __launch_bounds__(SCAN_T)
void scan1_kernel(const int* __restrict__ cnt, int* __restrict__ pre,
                  int* __restrict__ bsums, int N) {
    int b = blockIdx.x, t = threadIdx.x;
    int base = b * SCAN_BLK + t * SCAN_E;
    int v[SCAN_E], s = 0;
#pragma unroll
    for (int j = 0; j < SCAN_E; j++) {
        int idx = base + j;
        v[j] = (idx < N) ? cnt[idx] : 0;
        s += v[j];
    }
    __shared__ int sd[SCAN_T];
    sd[t] = s;
    __syncthreads();
    for (int off = 1; off < SCAN_T; off <<= 1) {
        int x = (t >= off) ? sd[t - off] : 0;
        __syncthreads();
        sd[t] += x;
        __syncthreads();
    }
    if (t == SCAN_T - 1) bsums[b] = sd[t];
    int run = sd[t] - s;
#pragma unroll
    for (int j = 0; j < SCAN_E; j++) {
        int idx = base + j;
        if (idx < N) pre[idx] = run;
        run += v[j];
    }
}

__global__ void scan2_kernel(int* __restrict__ bsums, int* __restrict__ row_start,
                             int nb, int N) {
    int run = 0;
    for (int b = 0; b < nb; b++) {
        int t = bsums[b];
        bsums[b] = run;
        run += t;
    }
    row_start[N] = run;
}

__global__ __launch_bounds__(SCAN_T)
void scan3_kernel(int* __restrict__ pre, const int* __restrict__ bsums,
                  int* __restrict__ cursor, int nb, int N) {
    int b = blockIdx.x, t = threadIdx.x;
    int add = bsums[b];
    int base = b * SCAN_BLK + t * SCAN_E;
#pragma unroll
    for (int j = 0; j < SCAN_E; j++) {
        int idx = base + j;
        if (idx < N) {
            int val = pre[idx] + add;
            pre[idx] = val;
            cursor[idx] = val;
        }
    }
}

// --- bucket edges of all 3 relations into one per-node list ----------------
// stored value = r*N + src  (directly addresses hb[r][src])
__global__ __launch_bounds__(256)
void bucket_fill_kernel(const int* __restrict__ src, const int* __restrict__ dst,
                        int* __restrict__ cursor, int* __restrict__ esrc,
                        int E, int N) {
    int e = blockIdx.x * blockDim.x + threadIdx.x;
    int r = blockIdx.y;
    if (e >= E) return;
    int d = dst[(size_t)r * E + e];
    int pos = atomicAdd(cursor + d, 1);
    esrc[pos] = r * N + src[(size_t)r * E + e];
}

// --- pre-split W0/W1 into hi/lo bf16, transposed to [r][n][k] --------------
__global__ __launch_bounds__(256)
void prep_w_kernel(const float* __restrict__ W0, const float* __restrict__ W1,
                   u16* __restrict__ w0hi, u16* __restrict__ w0lo,
                   u16* __restrict__ w1hi, u16* __restrict__ w1lo) {
    int idx = blockIdx.x * blockDim.x + threadIdx.x;
    const int n0 = 3 * 256 * 128;
    const int n1 = 3 * 128 * 128;
    if (idx >= n0 + n1) return;
    float f;
    u16 *phi, *plo;
    int oidx;
    if (idx < n0) {
        int r = idx / 32768, rem = idx % 32768;
        int n = rem / 256, k = rem % 256;
        f = W0[(size_t)r * 32768 + (size_t)k * 128 + n];
        phi = w0hi; plo = w0lo; oidx = idx;
    } else {
        int i2 = idx - n0;
        int r = i2 / 16384, rem = i2 % 16384;
        int n = rem / 128, k = rem % 128;
        f = W1[(size_t)r * 16384 + (size_t)k * 128 + n];
        phi = w1hi; plo = w1lo; oidx = i2;
    }
    uint32_t u = __float_as_uint(f);
    phi[oidx] = (u16)(u >> 16);                     // truncated hi
    float lo = f - __uint_as_float(u & 0xFFFF0000u);
    uint32_t ul = __float_as_uint(lo);
    plo[oidx] = (u16)((ul + 0x7FFFu + ((ul >> 16) & 1u)) >> 16);  // RTNE lo
}

// --- C_r[M x 128](bf16) = round_bf16((A * scale_r) @ W_r), r = blockIdx.y --
__global__ __launch_bounds__(256)
void gemm_split_bf16(const float* __restrict__ A, const float* __restrict__ s_out,
                     const u16* __restrict__ Whi_all, const u16* __restrict__ Wlo_all,
                     u16* __restrict__ Cout_all, int M, int K, int Nn) {
    const int r = blockIdx.y;
    const float* scale = s_out + (size_t)r * Nn;
    const u16* Whi = Whi_all + (size_t)r * K * 128;
    const u16* Wlo = Wlo_all + (size_t)r * K * 128;
    u16* Cout = Cout_all + (size_t)r * Nn * 128;

    __shared__ u16 As_hi[128][40];
    __shared__ u16 As_lo[128][40];
    __shared__ u16 Bs_hi[128][40];
    __shared__ u16 Bs_lo[128][40];

    const int tid  = threadIdx.x;
    const int m0   = blockIdx.x * 128;
    const int lane = tid & 63;
    const int wave = tid >> 6;
    const int wm   = (wave & 1) * 64;
    const int wn   = (wave >> 1) * 64;
    const int lm   = lane & 15;
    const int kq   = (lane >> 4) * 8;

    f32x4 acc[4][4];
#pragma unroll
    for (int i = 0; i < 4; i++)
#pragma unroll
        for (int j = 0; j < 4; j++) acc[i][j] = (f32x4){0.f, 0.f, 0.f, 0.f};

    const int srow = tid >> 1;
    const int skb  = (tid & 1) * 16;

    const bool valid = (m0 + srow) < M;
    const float sval = valid ? scale[m0 + srow] : 0.f;
    const float* arow = A + (size_t)(m0 + srow) * K;
    const u16* whrow = Whi + (size_t)srow * K;
    const u16* wlrow = Wlo + (size_t)srow * K;

    for (int k0 = 0; k0 < K; k0 += 32) {
        float fa[16];
        if (valid) {
            *(float4*)&fa[0]  = *(const float4*)(arow + k0 + skb);
            *(float4*)&fa[4]  = *(const float4*)(arow + k0 + skb + 4);
            *(float4*)&fa[8]  = *(const float4*)(arow + k0 + skb + 8);
            *(float4*)&fa[12] = *(const float4*)(arow + k0 + skb + 12);
        } else {
#pragma unroll
            for (int i = 0; i < 16; i++) fa[i] = 0.f;
        }
        uint32_t ah[8], al[8];
#pragma unroll
        for (int p = 0; p < 8; p++) {
            float f0 = fa[2 * p] * sval, f1 = fa[2 * p + 1] * sval;
            uint32_t u0 = __float_as_uint(f0), u1 = __float_as_uint(f1);
            ah[p] = (u0 >> 16) | (u1 & 0xFFFF0000u);
            float l0 = f0 - __uint_as_float(u0 & 0xFFFF0000u);
            float l1 = f1 - __uint_as_float(u1 & 0xFFFF0000u);
            al[p] = (__float_as_uint(l0) >> 16) | (__float_as_uint(l1) & 0xFFFF0000u);
        }
        *(uint4*)&As_hi[srow][skb]     = *(uint4*)&ah[0];
        *(uint4*)&As_hi[srow][skb + 8] = *(uint4*)&ah[4];
        *(uint4*)&As_lo[srow][skb]     = *(uint4*)&al[0];
        *(uint4*)&As_lo[srow][skb + 8] = *(uint4*)&al[4];

        *(uint4*)&Bs_hi[srow][skb]     = *(const uint4*)(whrow + k0 + skb);
        *(uint4*)&Bs_hi[srow][skb + 8] = *(const uint4*)(whrow + k0 + skb + 8);
        *(uint4*)&Bs_lo[srow][skb]     = *(const uint4*)(wlrow + k0 + skb);
        *(uint4*)&Bs_lo[srow][skb + 8] = *(const uint4*)(wlrow + k0 + skb + 8);

        __syncthreads();

        bf16x8 a_hi[4], a_lo[4], b_hi[4], b_lo[4];
#pragma unroll
        for (int i = 0; i < 4; i++) {
            a_hi[i] = *(const bf16x8*)&As_hi[wm + i * 16 + lm][kq];
            a_lo[i] = *(const bf16x8*)&As_lo[wm + i * 16 + lm][kq];
            b_hi[i] = *(const bf16x8*)&Bs_hi[wn + i * 16 + lm][kq];
            b_lo[i] = *(const bf16x8*)&Bs_lo[wn + i * 16 + lm][kq];
        }
#pragma unroll
        for (int i = 0; i < 4; i++)
#pragma unroll
            for (int j = 0; j < 4; j++) {
                acc[i][j] = __builtin_amdgcn_mfma_f32_16x16x32_bf16(a_hi[i], b_hi[j], acc[i][j], 0, 0, 0);
                acc[i][j] = __builtin_amdgcn_mfma_f32_16x16x32_bf16(a_lo[i], b_hi[j], acc[i][j], 0, 0, 0);
                acc[i][j] = __builtin_amdgcn_mfma_f32_16x16x32_bf16(a_hi[i], b_lo[j], acc[i][j], 0, 0, 0);
            }
        __syncthreads();
    }

    const int rq = (lane >> 4) * 4;
#pragma unroll
    for (int i = 0; i < 4; i++) {
        int mbase = m0 + wm + i * 16 + rq;
#pragma unroll
        for (int j = 0; j < 4; j++) {
            int col = wn + j * 16 + lm;
#pragma unroll
            for (int rg = 0; rg < 4; rg++) {
                int m = mbase + rg;
                if (m < M) {
                    uint32_t u = __float_as_uint(acc[i][j][rg]);
                    Cout[(size_t)m * 128 + col] =
                        (u16)((u + 0x7FFFu + ((u >> 16) & 1u)) >> 16);
                }
            }
        }
    }
}

// --- combined-CSR gather: one wave per node, 2 edges per load instruction --
// lanes 0-31 handle even edge slots, lanes 32-63 odd; each lane covers 4 cols
// (dwordx2 = 4 bf16). Edge indices live in registers (cooperative load +
// __shfl broadcast) so all gather loads are independent -> 8 lines in flight.
__device__ __forceinline__ void gather_all(const u16* __restrict__ hb,
                                           const int* __restrict__ row_start,
                                           const int* __restrict__ esrc,
                                           const float* __restrict__ s_in,
                                           int node, int lane, int N,
                                           float acc[4]) {
    const uint32_t* hrow = (const uint32_t*)hb + (lane & 31) * 2;
    const int slot = lane >> 5;
    const int N2 = N * 2;
    const float w0 = s_in[node];
    const float w1 = s_in[(size_t)N + node];
    const float w2 = s_in[(size_t)N2 + node];
    const int beg = row_start[node];
    const int end = row_start[node + 1];
    acc[0] = acc[1] = acc[2] = acc[3] = 0.f;
    for (int base = beg; base < end; base += 64) {
        int cn = end - base;
        cn = cn > 64 ? 64 : cn;
        int cidx = esrc[base + lane];   // over-read covered by padding
        for (int j = 0; j < cn; j += 8) {
            uint2 u[4];
            float w[4];
#pragma unroll
            for (int p = 0; p < 4; p++) {
                int jj = j + 2 * p + slot;
                int idx = __shfl(cidx, jj);
                float ws = (idx >= N) ? ((idx >= N2) ? w2 : w1) : w0;
                bool act = jj < cn;
                w[p] = act ? ws : 0.f;
                idx = act ? idx : 0;
                u[p] = *(const uint2*)(hrow + (size_t)idx * 64);
            }
#pragma unroll
            for (int p = 0; p < 4; p++) {
                acc[0] = fmaf(__uint_as_float(u[p].x << 16),          w[p], acc[0]);
                acc[1] = fmaf(__uint_as_float(u[p].x & 0xFFFF0000u),  w[p], acc[1]);
                acc[2] = fmaf(__uint_as_float(u[p].y << 16),          w[p], acc[2]);
                acc[3] = fmaf(__uint_as_float(u[p].y & 0xFFFF0000u),  w[p], acc[3]);
            }
        }
    }
#pragma unroll
    for (int k = 0; k < 4; k++) acc[k] += __shfl_xor(acc[k], 32);
}

// --- fused gather layer 0: combined CSR + bias + leakyReLU -> acc0 (fp32) --
__global__ __launch_bounds__(256)
void gather_l0(const u16* __restrict__ hb, const int* __restrict__ row_start,
               const int* __restrict__ esrc, const float* __restrict__ s_in,
               const float* __restrict__ b, float* __restrict__ out, int N) {
    int node = blockIdx.x * 4 + (threadIdx.x >> 6);
    if (node >= N) return;
    int lane = threadIdx.x & 63;
    float acc[4];
    gather_all(hb, row_start, esrc, s_in, node, lane, N, acc);
    int c0 = (lane & 31) * 4;
    float4 o;
    float* po = (float*)&o;
#pragma unroll
    for (int k = 0; k < 4; k++) {
        float v = acc[k] + b[c0 + k] + b[128 + c0 + k] + b[256 + c0 + k];
        po[k] = fmaxf(v, 0.f) + 0.01f * fminf(v, 0.f);
    }
    if (lane < 32) *(float4*)(out + (size_t)node * 128 + c0) = o;
}

// --- fused gather layer 1: combined CSR + bias -> out_h; + logits ----------
__global__ __launch_bounds__(256)
void gather_l1(const u16* __restrict__ hb, const int* __restrict__ row_start,
               const int* __restrict__ esrc, const float* __restrict__ s_in,
               const float* __restrict__ b, const float* __restrict__ fcW,
               const float* __restrict__ fcb, float* __restrict__ out_h,
               float* __restrict__ out_logits, int N) {
    int node = blockIdx.x * 4 + (threadIdx.x >> 6);
    if (node >= N) return;
    int lane = threadIdx.x & 63;
    float acc[4];
    gather_all(hb, row_start, esrc, s_in, node, lane, N, acc);
    int c0 = (lane & 31) * 4;
    float v[4];
#pragma unroll
    for (int k = 0; k < 4; k++)
        v[k] = acc[k] + b[c0 + k] + b[128 + c0 + k] + b[256 + c0 + k];
    if (lane < 32) {
        float4 o = make_float4(v[0], v[1], v[2], v[3]);
        *(float4*)(out_h + (size_t)node * 128 + c0) = o;
    }

    // logits: p[j] = sum_c h[c] * fcW[c][j]; reduce over the 32-lane group
    float p[16];
#pragma unroll
    for (int jj = 0; jj < 16; jj++) {
        p[jj] = v[0] * fcW[(size_t)(c0 + 0) * 16 + jj]
              + v[1] * fcW[(size_t)(c0 + 1) * 16 + jj]
              + v[2] * fcW[(size_t)(c0 + 2) * 16 + jj]
              + v[3] * fcW[(size_t)(c0 + 3) * 16 + jj];
    }
#pragma unroll
    for (int off = 1; off <= 16; off <<= 1) {
#pragma unroll
        for (int jj = 0; jj < 16; jj++) p[jj] += __shfl_xor(p[jj], off);
    }
    if (lane == 0) {
        float* lp = out_logits + (size_t)node * 16;
        *(float4*)(lp + 0)  = make_float4(p[0] + fcb[0],  p[1] + fcb[1],  p[2] + fcb[2],  p[3] + fcb[3]);
        *(float4*)(lp + 4)  = make_float4(p[4] + fcb[4],  p[5] + fcb[5],  p[6] + fcb[6],  p[7] + fcb[7]);
        *(float4*)(lp + 8)  = make_float4(p[8] + fcb[8],  p[9] + fcb[9],  p[10] + fcb[10], p[11] + fcb[11]);
        *(float4*)(lp + 12) = make_float4(p[12] + fcb[12], p[13] + fcb[13], p[14] + fcb[14], p[15] + fcb[15]);
    }
}

extern "C" void kernel_launch(void* const* d_in, const int* in_sizes, int n_in,
                              void* d_out, int out_size, void* d_ws, size_t ws_size,
                              hipStream_t stream) {
    const float* x   = (const float*)d_in[0];
    const int*   src = (const int*)d_in[1];
    const int*   dst = (const int*)d_in[2];
    const float* W0  = (const float*)d_in[3];
    const float* b0  = (const float*)d_in[4];
    const float* W1  = (const float*)d_in[5];
    const float* b1  = (const float*)d_in[6];
    const float* fcW = (const float*)d_in[7];
    const float* fcb = (const float*)d_in[8];

    const int N = in_sizes[0] / 256;   // 100000
    const int E = in_sizes[1] / 3;     // 600000
    const int nb = (N + SCAN_BLK - 1) / SCAN_BLK;

    float* out_h      = (float*)d_out;
    float* out_logits = out_h + (size_t)N * 128;

    char* p = (char*)d_ws;
    auto alloc = [&](size_t bytes) -> char* {
        char* q = p;
        p += (bytes + 255) & ~(size_t)255;
        return q;
    };
    float* s_out     = (float*)alloc(3 * (size_t)N * 4);
    float* s_in      = (float*)alloc(3 * (size_t)N * 4);
    int*   cnt8      = (int*)alloc(2 * 8 * 3 * (size_t)N * 4);  // out8 then in8
    int*   cnt_out8  = cnt8;
    int*   cnt_in8   = cnt8 + 8 * 3 * (size_t)N;
    int*   cnt_all   = (int*)alloc((size_t)N * 4);
    int*   row_start = (int*)alloc((size_t)(N + 1) * 4);
    int*   cursor    = (int*)alloc((size_t)N * 4);
    int*   bsums     = (int*)alloc(1024 * 4);
    int*   esrc      = (int*)alloc(3 * (size_t)E * 4 + 256);    // +pad for over-read
    u16*   w0hi      = (u16*)alloc(3 * 256 * 128 * 2);
    u16*   w0lo      = (u16*)alloc(3 * 256 * 128 * 2);
    u16*   w1hi      = (u16*)alloc(3 * 128 * 128 * 2);
    u16*   w1lo      = (u16*)alloc(3 * 128 * 128 * 2);
    u16*   hb        = (u16*)alloc(3 * (size_t)N * 128 * 2);
    float* acc0      = (float*)alloc((size_t)N * 128 * 4);

    hipMemsetAsync(cnt8, 0, 2 * 8 * 3 * (size_t)N * sizeof(int), stream);

    hist_kernel<<<dim3((E + 255) / 256, 3), 256, 0, stream>>>(src, dst, cnt_out8, cnt_in8, E, N);
    reduce_scales_kernel<<<(N + 255) / 256, 256, 0, stream>>>(
        cnt_out8, cnt_in8, s_out, s_in, cnt_all, N);

    scan1_kernel<<<nb, SCAN_T, 0, stream>>>(cnt_all, row_start, bsums, N);
    scan2_kernel<<<1, 1, 0, stream>>>(bsums, row_start, nb, N);
    scan3_kernel<<<nb, SCAN_T, 0, stream>>>(row_start, bsums, cursor, nb, N);
    bucket_fill_kernel<<<dim3((E + 255) / 256, 3), 256, 0, stream>>>(src, dst, cursor, esrc, E, N);

    prep_w_kernel<<<(3 * 256 * 128 + 3 * 128 * 128 + 255) / 256, 256, 0, stream>>>(
        W0, W1, w0hi, w0lo, w1hi, w1lo);

    int gemm_blocks   = (N + 127) / 128;
    int gather_blocks = (N + 3) / 4;

    // Layer 0: x[N,256] -> hb[r][N,128] bf16 -> acc0[N,128] fp32
    gemm_split_bf16<<<dim3(gemm_blocks, 3), 256, 0, stream>>>(
        x, s_out, w0hi, w0lo, hb, N, 256, N);
    gather_l0<<<gather_blocks, 256, 0, stream>>>(hb, row_start, esrc, s_in, b0, acc0, N);

    // Layer 1: acc0[N,128] -> hb[r][N,128] bf16 -> out_h + logits
    gemm_split_bf16<<<dim3(gemm_blocks, 3), 256, 0, stream>>>(
        acc0, s_out, w1hi, w1lo, hb, N, 128, N);
    gather_l1<<<gather_blocks, 256, 0, stream>>>(hb, row_start, esrc, s_in, b1, fcW, fcb,
                                                 out_h, out_logits, N);
}

// Round 2
// 784.560 us; speedup vs baseline: 1.1468x; 1.1468x over previous
//
#include <hip/hip_runtime.h>
#include <hip/hip_bf16.h>
#include <stdint.h>

// ---------------------------------------------------------------------------
// HeteroTextGCN round 6:
//  - gather: combined 3-relation CSR (kept), but index distribution via
//    wave-uniform scalar loads (readfirstlane'd row bounds) — NO shfl in the
//    address chain. 8 predicated edges per batch -> 8 row loads in flight.
//  - hist/scan/bucket/prep/GEMM: unchanged from round 5
// ---------------------------------------------------------------------------

typedef __attribute__((ext_vector_type(8))) short bf16x8;
typedef __attribute__((ext_vector_type(4))) float f32x4;
typedef unsigned short u16;

#define SCAN_T 256
#define SCAN_E 8
#define SCAN_BLK (SCAN_T * SCAN_E)

// --- degree histograms into 8 per-XCD copies -------------------------------
__global__ __launch_bounds__(256)
void hist_kernel(const int* __restrict__ src, const int* __restrict__ dst,
                 int* __restrict__ cnt_out8, int* __restrict__ cnt_in8,
                 int E, int N) {
    int e = blockIdx.x * blockDim.x + threadIdx.x;
    int r = blockIdx.y;
    if (e >= E) return;
    int copy = blockIdx.x & 7;
    size_t base = ((size_t)copy * 3 + r) * N;
    atomicAdd(cnt_out8 + base + src[(size_t)r * E + e], 1);
    atomicAdd(cnt_in8  + base + dst[(size_t)r * E + e], 1);
}

// --- reduce 8 copies + rsqrt scales + combined (all-relation) in-degree ----
__global__ __launch_bounds__(256)
void reduce_scales_kernel(const int* __restrict__ cnt_out8, const int* __restrict__ cnt_in8,
                          float* __restrict__ s_out, float* __restrict__ s_in,
                          int* __restrict__ cnt_all, int N) {
    int n = blockIdx.x * blockDim.x + threadIdx.x;
    if (n >= N) return;
    int tot = 0;
#pragma unroll
    for (int r = 0; r < 3; r++) {
        int co = 0, ci = 0;
#pragma unroll
        for (int c = 0; c < 8; c++) {
            co += cnt_out8[((size_t)c * 3 + r) * N + n];
            ci += cnt_in8[((size_t)c * 3 + r) * N + n];
        }
        s_out[(size_t)r * N + n] = rsqrtf(fmaxf((float)co, 1.0f));
        s_in[(size_t)r * N + n]  = rsqrtf(fmaxf((float)ci, 1.0f));
        tot += ci;
    }
    cnt_all[n] = tot;
}

// --- exclusive scan over combined in-degree (single row) -------------------
__global__ __launch_bounds__(SCAN_T)
void scan1_kernel(const int* __restrict__ cnt, int* __restrict__ pre,
                  int* __restrict__ bsums, int N) {
    int b = blockIdx.x, t = threadIdx.x;
    int base = b * SCAN_BLK + t * SCAN_E;
    int v[SCAN_E], s = 0;
#pragma unroll
    for (int j = 0; j < SCAN_E; j++) {
        int idx = base + j;
        v[j] = (idx < N) ? cnt[idx] : 0;
        s += v[j];
    }
    __shared__ int sd[SCAN_T];
    sd[t] = s;
    __syncthreads();
    for (int off = 1; off < SCAN_T; off <<= 1) {
        int x = (t >= off) ? sd[t - off] : 0;
        __syncthreads();
        sd[t] += x;
        __syncthreads();
    }
    if (t == SCAN_T - 1) bsums[b] = sd[t];
    int run = sd[t] - s;
#pragma unroll
    for (int j = 0; j < SCAN_E; j++) {
        int idx = base + j;
        if (idx < N) pre[idx] = run;
        run += v[j];
    }
}

__global__ void scan2_kernel(int* __restrict__ bsums, int* __restrict__ row_start,
                             int nb, int N) {
    int run = 0;
    for (int b = 0; b < nb; b++) {
        int t = bsums[b];
        bsums[b] = run;
        run += t;
    }
    row_start[N] = run;
}

__global__ __launch_bounds__(SCAN_T)
void scan3_kernel(int* __restrict__ pre, const int* __restrict__ bsums,
                  int* __restrict__ cursor, int nb, int N) {
    int b = blockIdx.x, t = threadIdx.x;
    int add = bsums[b];
    int base = b * SCAN_BLK + t * SCAN_E;
#pragma unroll
    for (int j = 0; j < SCAN_E; j++) {
        int idx = base + j;
        if (idx < N) {
            int val = pre[idx] + add;
            pre[idx] = val;
            cursor[idx] = val;
        }
    }
}

// --- bucket edges of all 3 relations into one per-node list ----------------
// stored value = r*N + src  (directly addresses hb[r][src])
__global__ __launch_bounds__(256)
void bucket_fill_kernel(const int* __restrict__ src, const int* __restrict__ dst,
                        int* __restrict__ cursor, int* __restrict__ esrc,
                        int E, int N) {
    int e = blockIdx.x * blockDim.x + threadIdx.x;
    int r = blockIdx.y;
    if (e >= E) return;
    int d = dst[(size_t)r * E + e];
    int pos = atomicAdd(cursor + d, 1);
    esrc[pos] = r * N + src[(size_t)r * E + e];
}

// --- pre-split W0/W1 into hi/lo bf16, transposed to [r][n][k] --------------
__global__ __launch_bounds__(256)
void prep_w_kernel(const float* __restrict__ W0, const float* __restrict__ W1,
                   u16* __restrict__ w0hi, u16* __restrict__ w0lo,
                   u16* __restrict__ w1hi, u16* __restrict__ w1lo) {
    int idx = blockIdx.x * blockDim.x + threadIdx.x;
    const int n0 = 3 * 256 * 128;
    const int n1 = 3 * 128 * 128;
    if (idx >= n0 + n1) return;
    float f;
    u16 *phi, *plo;
    int oidx;
    if (idx < n0) {
        int r = idx / 32768, rem = idx % 32768;
        int n = rem / 256, k = rem % 256;
        f = W0[(size_t)r * 32768 + (size_t)k * 128 + n];
        phi = w0hi; plo = w0lo; oidx = idx;
    } else {
        int i2 = idx - n0;
        int r = i2 / 16384, rem = i2 % 16384;
        int n = rem / 128, k = rem % 128;
        f = W1[(size_t)r * 16384 + (size_t)k * 128 + n];
        phi = w1hi; plo = w1lo; oidx = i2;
    }
    uint32_t u = __float_as_uint(f);
    phi[oidx] = (u16)(u >> 16);                     // truncated hi
    float lo = f - __uint_as_float(u & 0xFFFF0000u);
    uint32_t ul = __float_as_uint(lo);
    plo[oidx] = (u16)((ul + 0x7FFFu + ((ul >> 16) & 1u)) >> 16);  // RTNE lo
}

// --- C_r[M x 128](bf16) = round_bf16((A * scale_r) @ W_r), r = blockIdx.y --
__global__ __launch_bounds__(256)
void gemm_split_bf16(const float* __restrict__ A, const float* __restrict__ s_out,
                     const u16* __restrict__ Whi_all, const u16* __restrict__ Wlo_all,
                     u16* __restrict__ Cout_all, int M, int K, int Nn) {
    const int r = blockIdx.y;
    const float* scale = s_out + (size_t)r * Nn;
    const u16* Whi = Whi_all + (size_t)r * K * 128;
    const u16* Wlo = Wlo_all + (size_t)r * K * 128;
    u16* Cout = Cout_all + (size_t)r * Nn * 128;

    __shared__ u16 As_hi[128][40];
    __shared__ u16 As_lo[128][40];
    __shared__ u16 Bs_hi[128][40];
    __shared__ u16 Bs_lo[128][40];

    const int tid  = threadIdx.x;
    const int m0   = blockIdx.x * 128;
    const int lane = tid & 63;
    const int wave = tid >> 6;
    const int wm   = (wave & 1) * 64;
    const int wn   = (wave >> 1) * 64;
    const int lm   = lane & 15;
    const int kq   = (lane >> 4) * 8;

    f32x4 acc[4][4];
#pragma unroll
    for (int i = 0; i < 4; i++)
#pragma unroll
        for (int j = 0; j < 4; j++) acc[i][j] = (f32x4){0.f, 0.f, 0.f, 0.f};

    const int srow = tid >> 1;
    const int skb  = (tid & 1) * 16;

    const bool valid = (m0 + srow) < M;
    const float sval = valid ? scale[m0 + srow] : 0.f;
    const float* arow = A + (size_t)(m0 + srow) * K;
    const u16* whrow = Whi + (size_t)srow * K;
    const u16* wlrow = Wlo + (size_t)srow * K;

    for (int k0 = 0; k0 < K; k0 += 32) {
        float fa[16];
        if (valid) {
            *(float4*)&fa[0]  = *(const float4*)(arow + k0 + skb);
            *(float4*)&fa[4]  = *(const float4*)(arow + k0 + skb + 4);
            *(float4*)&fa[8]  = *(const float4*)(arow + k0 + skb + 8);
            *(float4*)&fa[12] = *(const float4*)(arow + k0 + skb + 12);
        } else {
#pragma unroll
            for (int i = 0; i < 16; i++) fa[i] = 0.f;
        }
        uint32_t ah[8], al[8];
#pragma unroll
        for (int p = 0; p < 8; p++) {
            float f0 = fa[2 * p] * sval, f1 = fa[2 * p + 1] * sval;
            uint32_t u0 = __float_as_uint(f0), u1 = __float_as_uint(f1);
            ah[p] = (u0 >> 16) | (u1 & 0xFFFF0000u);
            float l0 = f0 - __uint_as_float(u0 & 0xFFFF0000u);
            float l1 = f1 - __uint_as_float(u1 & 0xFFFF0000u);
            al[p] = (__float_as_uint(l0) >> 16) | (__float_as_uint(l1) & 0xFFFF0000u);
        }
        *(uint4*)&As_hi[srow][skb]     = *(uint4*)&ah[0];
        *(uint4*)&As_hi[srow][skb + 8] = *(uint4*)&ah[4];
        *(uint4*)&As_lo[srow][skb]     = *(uint4*)&al[0];
        *(uint4*)&As_lo[srow][skb + 8] = *(uint4*)&al[4];

        *(uint4*)&Bs_hi[srow][skb]     = *(const uint4*)(whrow + k0 + skb);
        *(uint4*)&Bs_hi[srow][skb + 8] = *(const uint4*)(whrow + k0 + skb + 8);
        *(uint4*)&Bs_lo[srow][skb]     = *(const uint4*)(wlrow + k0 + skb);
        *(uint4*)&Bs_lo[srow][skb + 8] = *(const uint4*)(wlrow + k0 + skb + 8);

        __syncthreads();

        bf16x8 a_hi[4], a_lo[4], b_hi[4], b_lo[4];
#pragma unroll
        for (int i = 0; i < 4; i++) {
            a_hi[i] = *(const bf16x8*)&As_hi[wm + i * 16 + lm][kq];
            a_lo[i] = *(const bf16x8*)&As_lo[wm + i * 16 + lm][kq];
            b_hi[i] = *(const bf16x8*)&Bs_hi[wn + i * 16 + lm][kq];
            b_lo[i] = *(const bf16x8*)&Bs_lo[wn + i * 16 + lm][kq];
        }
#pragma unroll
        for (int i = 0; i < 4; i++)
#pragma unroll
            for (int j = 0; j < 4; j++) {
                acc[i][j] = __builtin_amdgcn_mfma_f32_16x16x32_bf16(a_hi[i], b_hi[j], acc[i][j], 0, 0, 0);
                acc[i][j] = __builtin_amdgcn_mfma_f32_16x16x32_bf16(a_lo[i], b_hi[j], acc[i][j], 0, 0, 0);
                acc[i][j] = __builtin_amdgcn_mfma_f32_16x16x32_bf16(a_hi[i], b_lo[j], acc[i][j], 0, 0, 0);
            }
        __syncthreads();
    }

    const int rq = (lane >> 4) * 4;
#pragma unroll
    for (int i = 0; i < 4; i++) {
        int mbase = m0 + wm + i * 16 + rq;
#pragma unroll
        for (int j = 0; j < 4; j++) {
            int col = wn + j * 16 + lm;
#pragma unroll
            for (int rg = 0; rg < 4; rg++) {
                int m = mbase + rg;
                if (m < M) {
                    uint32_t u = __float_as_uint(acc[i][j][rg]);
                    Cout[(size_t)m * 128 + col] =
                        (u16)((u + 0x7FFFu + ((u >> 16) & 1u)) >> 16);
                }
            }
        }
    }
}

#define BF16_LO(u) __uint_as_float((u) << 16)
#define BF16_HI(u) __uint_as_float((u) & 0xFFFF0000u)

// --- combined-CSR gather, wave-uniform index loads, 8 rows in flight -------
// One wave per node; lane covers cols [2*lane, 2*lane+1] (dword per row).
// Row bounds readfirstlane'd to SGPR -> index loads are uniform (scalar
// pipe / broadcast), independent of row loads. Per-edge relation weight
// selected by comparing idx against N, 2N.
__device__ __forceinline__ void gather_all(const uint32_t* __restrict__ hb32,
                                           const int* __restrict__ row_start,
                                           const int* __restrict__ esrc,
                                           const float* __restrict__ s_in,
                                           int node, int lane, int N,
                                           float& ox, float& oy) {
    const uint32_t* hrow = hb32 + lane;
    const int N2 = N * 2;
    const float w0 = s_in[node];
    const float w1 = s_in[(size_t)N + node];
    const float w2 = s_in[(size_t)N2 + node];
    const int beg = __builtin_amdgcn_readfirstlane(row_start[node]);
    const int end = __builtin_amdgcn_readfirstlane(row_start[node + 1]);
    float ax = 0.f, ay = 0.f, bx = 0.f, by = 0.f;
    float cx = 0.f, cy = 0.f, dx = 0.f, dy = 0.f;
    for (int e = beg; e < end; e += 8) {
        const int rem = end - e;   // uniform
        uint32_t u[8];
        float w[8];
#pragma unroll
        for (int p = 0; p < 8; p++) {
            int idx = esrc[e + p];                 // uniform addr (pad-covered)
            float ws = (idx < N) ? w0 : ((idx < N2) ? w1 : w2);
            bool act = p < rem;
            w[p] = act ? ws : 0.f;
            idx = act ? idx : 0;
            u[p] = hrow[(size_t)idx * 64];         // 256B row, 8 in flight
        }
#pragma unroll
        for (int p = 0; p < 8; p += 4) {
            ax = fmaf(BF16_LO(u[p]),     w[p],     ax);
            ay = fmaf(BF16_HI(u[p]),     w[p],     ay);
            bx = fmaf(BF16_LO(u[p + 1]), w[p + 1], bx);
            by = fmaf(BF16_HI(u[p + 1]), w[p + 1], by);
            cx = fmaf(BF16_LO(u[p + 2]), w[p + 2], cx);
            cy = fmaf(BF16_HI(u[p + 2]), w[p + 2], cy);
            dx = fmaf(BF16_LO(u[p + 3]), w[p + 3], dx);
            dy = fmaf(BF16_HI(u[p + 3]), w[p + 3], dy);
        }
    }
    ox = (ax + bx) + (cx + dx);
    oy = (ay + by) + (cy + dy);
}

// --- fused gather layer 0: combined CSR + bias + leakyReLU -> acc0 (fp32) --
__global__ __launch_bounds__(256)
void gather_l0(const u16* __restrict__ hb, const int* __restrict__ row_start,
               const int* __restrict__ esrc, const float* __restrict__ s_in,
               const float* __restrict__ b, float* __restrict__ out, int N) {
    int node = blockIdx.x * 4 + (threadIdx.x >> 6);
    if (node >= N) return;
    int lane = threadIdx.x & 63;
    float tx, ty;
    gather_all((const uint32_t*)hb, row_start, esrc, s_in, node, lane, N, tx, ty);
    int c0 = lane * 2;
    tx += b[c0] + b[128 + c0] + b[256 + c0];
    ty += b[c0 + 1] + b[128 + c0 + 1] + b[256 + c0 + 1];
    tx = fmaxf(tx, 0.f) + 0.01f * fminf(tx, 0.f);
    ty = fmaxf(ty, 0.f) + 0.01f * fminf(ty, 0.f);
    *(float2*)(out + (size_t)node * 128 + c0) = make_float2(tx, ty);
}

// --- fused gather layer 1: combined CSR + bias -> out_h; + logits ----------
__global__ __launch_bounds__(256)
void gather_l1(const u16* __restrict__ hb, const int* __restrict__ row_start,
               const int* __restrict__ esrc, const float* __restrict__ s_in,
               const float* __restrict__ b, const float* __restrict__ fcW,
               const float* __restrict__ fcb, float* __restrict__ out_h,
               float* __restrict__ out_logits, int N) {
    int node = blockIdx.x * 4 + (threadIdx.x >> 6);
    if (node >= N) return;
    int lane = threadIdx.x & 63;
    float tx, ty;
    gather_all((const uint32_t*)hb, row_start, esrc, s_in, node, lane, N, tx, ty);
    int c0 = lane * 2;
    tx += b[c0] + b[128 + c0] + b[256 + c0];
    ty += b[c0 + 1] + b[128 + c0 + 1] + b[256 + c0 + 1];
    *(float2*)(out_h + (size_t)node * 128 + c0) = make_float2(tx, ty);

    const float* fc0 = fcW + (size_t)c0 * 16;
    float p[16];
#pragma unroll
    for (int j = 0; j < 16; j++) p[j] = tx * fc0[j] + ty * fc0[16 + j];
#pragma unroll
    for (int off = 1; off < 64; off <<= 1) {
#pragma unroll
        for (int j = 0; j < 16; j++) p[j] += __shfl_xor(p[j], off);
    }
    if (lane == 0) {
        float* lp = out_logits + (size_t)node * 16;
        *(float4*)(lp + 0)  = make_float4(p[0] + fcb[0],  p[1] + fcb[1],  p[2] + fcb[2],  p[3] + fcb[3]);
        *(float4*)(lp + 4)  = make_float4(p[4] + fcb[4],  p[5] + fcb[5],  p[6] + fcb[6],  p[7] + fcb[7]);
        *(float4*)(lp + 8)  = make_float4(p[8] + fcb[8],  p[9] + fcb[9],  p[10] + fcb[10], p[11] + fcb[11]);
        *(float4*)(lp + 12) = make_float4(p[12] + fcb[12], p[13] + fcb[13], p[14] + fcb[14], p[15] + fcb[15]);
    }
}

extern "C" void kernel_launch(void* const* d_in, const int* in_sizes, int n_in,
                              void* d_out, int out_size, void* d_ws, size_t ws_size,
                              hipStream_t stream) {
    const float* x   = (const float*)d_in[0];
    const int*   src = (const int*)d_in[1];
    const int*   dst = (const int*)d_in[2];
    const float* W0  = (const float*)d_in[3];
    const float* b0  = (const float*)d_in[4];
    const float* W1  = (const float*)d_in[5];
    const float* b1  = (const float*)d_in[6];
    const float* fcW = (const float*)d_in[7];
    const float* fcb = (const float*)d_in[8];

    const int N = in_sizes[0] / 256;   // 100000
    const int E = in_sizes[1] / 3;     // 600000
    const int nb = (N + SCAN_BLK - 1) / SCAN_BLK;

    float* out_h      = (float*)d_out;
    float* out_logits = out_h + (size_t)N * 128;

    char* p = (char*)d_ws;
    auto alloc = [&](size_t bytes) -> char* {
        char* q = p;
        p += (bytes + 255) & ~(size_t)255;
        return q;
    };
    float* s_out     = (float*)alloc(3 * (size_t)N * 4);
    float* s_in      = (float*)alloc(3 * (size_t)N * 4);
    int*   cnt8      = (int*)alloc(2 * 8 * 3 * (size_t)N * 4);  // out8 then in8
    int*   cnt_out8  = cnt8;
    int*   cnt_in8   = cnt8 + 8 * 3 * (size_t)N;
    int*   cnt_all   = (int*)alloc((size_t)N * 4);
    int*   row_start = (int*)alloc((size_t)(N + 1) * 4);
    int*   cursor    = (int*)alloc((size_t)N * 4);
    int*   bsums     = (int*)alloc(1024 * 4);
    int*   esrc      = (int*)alloc(3 * (size_t)E * 4 + 256);    // +pad for over-read
    u16*   w0hi      = (u16*)alloc(3 * 256 * 128 * 2);
    u16*   w0lo      = (u16*)alloc(3 * 256 * 128 * 2);
    u16*   w1hi      = (u16*)alloc(3 * 128 * 128 * 2);
    u16*   w1lo      = (u16*)alloc(3 * 128 * 128 * 2);
    u16*   hb        = (u16*)alloc(3 * (size_t)N * 128 * 2);
    float* acc0      = (float*)alloc((size_t)N * 128 * 4);

    hipMemsetAsync(cnt8, 0, 2 * 8 * 3 * (size_t)N * sizeof(int), stream);

    hist_kernel<<<dim3((E + 255) / 256, 3), 256, 0, stream>>>(src, dst, cnt_out8, cnt_in8, E, N);
    reduce_scales_kernel<<<(N + 255) / 256, 256, 0, stream>>>(
        cnt_out8, cnt_in8, s_out, s_in, cnt_all, N);

    scan1_kernel<<<nb, SCAN_T, 0, stream>>>(cnt_all, row_start, bsums, N);
    scan2_kernel<<<1, 1, 0, stream>>>(bsums, row_start, nb, N);
    scan3_kernel<<<nb, SCAN_T, 0, stream>>>(row_start, bsums, cursor, nb, N);
    bucket_fill_kernel<<<dim3((E + 255) / 256, 3), 256, 0, stream>>>(src, dst, cursor, esrc, E, N);

    prep_w_kernel<<<(3 * 256 * 128 + 3 * 128 * 128 + 255) / 256, 256, 0, stream>>>(
        W0, W1, w0hi, w0lo, w1hi, w1lo);

    int gemm_blocks   = (N + 127) / 128;
    int gather_blocks = (N + 3) / 4;

    // Layer 0: x[N,256] -> hb[r][N,128] bf16 -> acc0[N,128] fp32
    gemm_split_bf16<<<dim3(gemm_blocks, 3), 256, 0, stream>>>(
        x, s_out, w0hi, w0lo, hb, N, 256, N);
    gather_l0<<<gather_blocks, 256, 0, stream>>>(hb, row_start, esrc, s_in, b0, acc0, N);

    // Layer 1: acc0[N,128] -> hb[r][N,128] bf16 -> out_h + logits
    gemm_split_bf16<<<dim3(gemm_blocks, 3), 256, 0, stream>>>(
        acc0, s_out, w1hi, w1lo, hb, N, 128, N);
    gather_l1<<<gather_blocks, 256, 0, stream>>>(hb, row_start, esrc, s_in, b1, fcW, fcb,
                                                 out_h, out_logits, N);
}

// Round 3
// 758.463 us; speedup vs baseline: 1.1862x; 1.0344x over previous
//
#include <hip/hip_runtime.h>
#include <hip/hip_bf16.h>
#include <stdint.h>

// ---------------------------------------------------------------------------
// HeteroTextGCN round 7:
//  - bucket_fill: 8 edges/thread phase-split (loads->atomics->stores),
//    cursor padded to 1 counter / 64B line (kills same-line atomic serialize)
//  - hist: 4 edges/thread phase-split
//  - gather/scan/prep/GEMM: unchanged from round 6
// ---------------------------------------------------------------------------

typedef __attribute__((ext_vector_type(8))) short bf16x8;
typedef __attribute__((ext_vector_type(4))) float f32x4;
typedef unsigned short u16;

#define SCAN_T 256
#define SCAN_E 8
#define SCAN_BLK (SCAN_T * SCAN_E)
#define CUR_PAD 16            // ints per cursor slot (64B line-exclusive)
#define BF_K 8                // edges per thread in bucket_fill
#define HIST_K 4              // edges per thread in hist

// --- degree histograms into 8 per-XCD copies, 4 edges/thread ---------------
__global__ __launch_bounds__(256)
void hist_kernel(const int* __restrict__ src, const int* __restrict__ dst,
                 int* __restrict__ cnt_out8, int* __restrict__ cnt_in8,
                 int E, int N) {
    int r = blockIdx.y;
    int e0 = blockIdx.x * (256 * HIST_K) + threadIdx.x;
    int copy = blockIdx.x & 7;
    size_t base = ((size_t)copy * 3 + r) * N;
    int s[HIST_K], d[HIST_K];
#pragma unroll
    for (int j = 0; j < HIST_K; j++) {
        int e = e0 + j * 256;
        bool v = e < E;
        s[j] = v ? src[(size_t)r * E + e] : -1;
        d[j] = v ? dst[(size_t)r * E + e] : -1;
    }
#pragma unroll
    for (int j = 0; j < HIST_K; j++)
        if (s[j] >= 0) atomicAdd(cnt_out8 + base + s[j], 1);
#pragma unroll
    for (int j = 0; j < HIST_K; j++)
        if (d[j] >= 0) atomicAdd(cnt_in8 + base + d[j], 1);
}

// --- reduce 8 copies + rsqrt scales + combined (all-relation) in-degree ----
__global__ __launch_bounds__(256)
void reduce_scales_kernel(const int* __restrict__ cnt_out8, const int* __restrict__ cnt_in8,
                          float* __restrict__ s_out, float* __restrict__ s_in,
                          int* __restrict__ cnt_all, int N) {
    int n = blockIdx.x * blockDim.x + threadIdx.x;
    if (n >= N) return;
    int tot = 0;
#pragma unroll
    for (int r = 0; r < 3; r++) {
        int co = 0, ci = 0;
#pragma unroll
        for (int c = 0; c < 8; c++) {
            co += cnt_out8[((size_t)c * 3 + r) * N + n];
            ci += cnt_in8[((size_t)c * 3 + r) * N + n];
        }
        s_out[(size_t)r * N + n] = rsqrtf(fmaxf((float)co, 1.0f));
        s_in[(size_t)r * N + n]  = rsqrtf(fmaxf((float)ci, 1.0f));
        tot += ci;
    }
    cnt_all[n] = tot;
}

// --- exclusive scan over combined in-degree (single row) -------------------
__global__ __launch_bounds__(SCAN_T)
void scan1_kernel(const int* __restrict__ cnt, int* __restrict__ pre,
                  int* __restrict__ bsums, int N) {
    int b = blockIdx.x, t = threadIdx.x;
    int base = b * SCAN_BLK + t * SCAN_E;
    int v[SCAN_E], s = 0;
#pragma unroll
    for (int j = 0; j < SCAN_E; j++) {
        int idx = base + j;
        v[j] = (idx < N) ? cnt[idx] : 0;
        s += v[j];
    }
    __shared__ int sd[SCAN_T];
    sd[t] = s;
    __syncthreads();
    for (int off = 1; off < SCAN_T; off <<= 1) {
        int x = (t >= off) ? sd[t - off] : 0;
        __syncthreads();
        sd[t] += x;
        __syncthreads();
    }
    if (t == SCAN_T - 1) bsums[b] = sd[t];
    int run = sd[t] - s;
#pragma unroll
    for (int j = 0; j < SCAN_E; j++) {
        int idx = base + j;
        if (idx < N) pre[idx] = run;
        run += v[j];
    }
}

__global__ void scan2_kernel(int* __restrict__ bsums, int* __restrict__ row_start,
                             int nb, int N) {
    int run = 0;
    for (int b = 0; b < nb; b++) {
        int t = bsums[b];
        bsums[b] = run;
        run += t;
    }
    row_start[N] = run;
}

__global__ __launch_bounds__(SCAN_T)
void scan3_kernel(int* __restrict__ pre, const int* __restrict__ bsums,
                  int* __restrict__ cursor, int nb, int N) {
    int b = blockIdx.x, t = threadIdx.x;
    int add = bsums[b];
    int base = b * SCAN_BLK + t * SCAN_E;
#pragma unroll
    for (int j = 0; j < SCAN_E; j++) {
        int idx = base + j;
        if (idx < N) {
            int val = pre[idx] + add;
            pre[idx] = val;
            cursor[(size_t)idx * CUR_PAD] = val;   // line-exclusive counter
        }
    }
}

// --- bucket edges of all 3 relations into one per-node list ----------------
// stored value = r*N + src  (directly addresses hb[r][src])
// 8 edges/thread, phase-split: loads -> atomics (8 in flight) -> stores
__global__ __launch_bounds__(256)
void bucket_fill_kernel(const int* __restrict__ src, const int* __restrict__ dst,
                        int* __restrict__ cursor, int* __restrict__ esrc,
                        int E, int N) {
    int r = blockIdx.y;
    int e0 = blockIdx.x * (256 * BF_K) + threadIdx.x;
    int s[BF_K], d[BF_K], pos[BF_K];
#pragma unroll
    for (int j = 0; j < BF_K; j++) {
        int e = e0 + j * 256;
        bool v = e < E;
        s[j] = v ? src[(size_t)r * E + e] : -1;
        d[j] = v ? dst[(size_t)r * E + e] : 0;
    }
#pragma unroll
    for (int j = 0; j < BF_K; j++)
        pos[j] = (s[j] >= 0) ? atomicAdd(cursor + (size_t)d[j] * CUR_PAD, 1) : 0;
#pragma unroll
    for (int j = 0; j < BF_K; j++)
        if (s[j] >= 0) esrc[pos[j]] = r * N + s[j];
}

// --- pre-split W0/W1 into hi/lo bf16, transposed to [r][n][k] --------------
__global__ __launch_bounds__(256)
void prep_w_kernel(const float* __restrict__ W0, const float* __restrict__ W1,
                   u16* __restrict__ w0hi, u16* __restrict__ w0lo,
                   u16* __restrict__ w1hi, u16* __restrict__ w1lo) {
    int idx = blockIdx.x * blockDim.x + threadIdx.x;
    const int n0 = 3 * 256 * 128;
    const int n1 = 3 * 128 * 128;
    if (idx >= n0 + n1) return;
    float f;
    u16 *phi, *plo;
    int oidx;
    if (idx < n0) {
        int r = idx / 32768, rem = idx % 32768;
        int n = rem / 256, k = rem % 256;
        f = W0[(size_t)r * 32768 + (size_t)k * 128 + n];
        phi = w0hi; plo = w0lo; oidx = idx;
    } else {
        int i2 = idx - n0;
        int r = i2 / 16384, rem = i2 % 16384;
        int n = rem / 128, k = rem % 128;
        f = W1[(size_t)r * 16384 + (size_t)k * 128 + n];
        phi = w1hi; plo = w1lo; oidx = i2;
    }
    uint32_t u = __float_as_uint(f);
    phi[oidx] = (u16)(u >> 16);                     // truncated hi
    float lo = f - __uint_as_float(u & 0xFFFF0000u);
    uint32_t ul = __float_as_uint(lo);
    plo[oidx] = (u16)((ul + 0x7FFFu + ((ul >> 16) & 1u)) >> 16);  // RTNE lo
}

// --- C_r[M x 128](bf16) = round_bf16((A * scale_r) @ W_r), r = blockIdx.y --
__global__ __launch_bounds__(256)
void gemm_split_bf16(const float* __restrict__ A, const float* __restrict__ s_out,
                     const u16* __restrict__ Whi_all, const u16* __restrict__ Wlo_all,
                     u16* __restrict__ Cout_all, int M, int K, int Nn) {
    const int r = blockIdx.y;
    const float* scale = s_out + (size_t)r * Nn;
    const u16* Whi = Whi_all + (size_t)r * K * 128;
    const u16* Wlo = Wlo_all + (size_t)r * K * 128;
    u16* Cout = Cout_all + (size_t)r * Nn * 128;

    __shared__ u16 As_hi[128][40];
    __shared__ u16 As_lo[128][40];
    __shared__ u16 Bs_hi[128][40];
    __shared__ u16 Bs_lo[128][40];

    const int tid  = threadIdx.x;
    const int m0   = blockIdx.x * 128;
    const int lane = tid & 63;
    const int wave = tid >> 6;
    const int wm   = (wave & 1) * 64;
    const int wn   = (wave >> 1) * 64;
    const int lm   = lane & 15;
    const int kq   = (lane >> 4) * 8;

    f32x4 acc[4][4];
#pragma unroll
    for (int i = 0; i < 4; i++)
#pragma unroll
        for (int j = 0; j < 4; j++) acc[i][j] = (f32x4){0.f, 0.f, 0.f, 0.f};

    const int srow = tid >> 1;
    const int skb  = (tid & 1) * 16;

    const bool valid = (m0 + srow) < M;
    const float sval = valid ? scale[m0 + srow] : 0.f;
    const float* arow = A + (size_t)(m0 + srow) * K;
    const u16* whrow = Whi + (size_t)srow * K;
    const u16* wlrow = Wlo + (size_t)srow * K;

    for (int k0 = 0; k0 < K; k0 += 32) {
        float fa[16];
        if (valid) {
            *(float4*)&fa[0]  = *(const float4*)(arow + k0 + skb);
            *(float4*)&fa[4]  = *(const float4*)(arow + k0 + skb + 4);
            *(float4*)&fa[8]  = *(const float4*)(arow + k0 + skb + 8);
            *(float4*)&fa[12] = *(const float4*)(arow + k0 + skb + 12);
        } else {
#pragma unroll
            for (int i = 0; i < 16; i++) fa[i] = 0.f;
        }
        uint32_t ah[8], al[8];
#pragma unroll
        for (int p = 0; p < 8; p++) {
            float f0 = fa[2 * p] * sval, f1 = fa[2 * p + 1] * sval;
            uint32_t u0 = __float_as_uint(f0), u1 = __float_as_uint(f1);
            ah[p] = (u0 >> 16) | (u1 & 0xFFFF0000u);
            float l0 = f0 - __uint_as_float(u0 & 0xFFFF0000u);
            float l1 = f1 - __uint_as_float(u1 & 0xFFFF0000u);
            al[p] = (__float_as_uint(l0) >> 16) | (__float_as_uint(l1) & 0xFFFF0000u);
        }
        *(uint4*)&As_hi[srow][skb]     = *(uint4*)&ah[0];
        *(uint4*)&As_hi[srow][skb + 8] = *(uint4*)&ah[4];
        *(uint4*)&As_lo[srow][skb]     = *(uint4*)&al[0];
        *(uint4*)&As_lo[srow][skb + 8] = *(uint4*)&al[4];

        *(uint4*)&Bs_hi[srow][skb]     = *(const uint4*)(whrow + k0 + skb);
        *(uint4*)&Bs_hi[srow][skb + 8] = *(const uint4*)(whrow + k0 + skb + 8);
        *(uint4*)&Bs_lo[srow][skb]     = *(const uint4*)(wlrow + k0 + skb);
        *(uint4*)&Bs_lo[srow][skb + 8] = *(const uint4*)(wlrow + k0 + skb + 8);

        __syncthreads();

        bf16x8 a_hi[4], a_lo[4], b_hi[4], b_lo[4];
#pragma unroll
        for (int i = 0; i < 4; i++) {
            a_hi[i] = *(const bf16x8*)&As_hi[wm + i * 16 + lm][kq];
            a_lo[i] = *(const bf16x8*)&As_lo[wm + i * 16 + lm][kq];
            b_hi[i] = *(const bf16x8*)&Bs_hi[wn + i * 16 + lm][kq];
            b_lo[i] = *(const bf16x8*)&Bs_lo[wn + i * 16 + lm][kq];
        }
#pragma unroll
        for (int i = 0; i < 4; i++)
#pragma unroll
            for (int j = 0; j < 4; j++) {
                acc[i][j] = __builtin_amdgcn_mfma_f32_16x16x32_bf16(a_hi[i], b_hi[j], acc[i][j], 0, 0, 0);
                acc[i][j] = __builtin_amdgcn_mfma_f32_16x16x32_bf16(a_lo[i], b_hi[j], acc[i][j], 0, 0, 0);
                acc[i][j] = __builtin_amdgcn_mfma_f32_16x16x32_bf16(a_hi[i], b_lo[j], acc[i][j], 0, 0, 0);
            }
        __syncthreads();
    }

    const int rq = (lane >> 4) * 4;
#pragma unroll
    for (int i = 0; i < 4; i++) {
        int mbase = m0 + wm + i * 16 + rq;
#pragma unroll
        for (int j = 0; j < 4; j++) {
            int col = wn + j * 16 + lm;
#pragma unroll
            for (int rg = 0; rg < 4; rg++) {
                int m = mbase + rg;
                if (m < M) {
                    uint32_t u = __float_as_uint(acc[i][j][rg]);
                    Cout[(size_t)m * 128 + col] =
                        (u16)((u + 0x7FFFu + ((u >> 16) & 1u)) >> 16);
                }
            }
        }
    }
}

#define BF16_LO(u) __uint_as_float((u) << 16)
#define BF16_HI(u) __uint_as_float((u) & 0xFFFF0000u)

// --- combined-CSR gather, wave-uniform index loads, 8 rows in flight -------
__device__ __forceinline__ void gather_all(const uint32_t* __restrict__ hb32,
                                           const int* __restrict__ row_start,
                                           const int* __restrict__ esrc,
                                           const float* __restrict__ s_in,
                                           int node, int lane, int N,
                                           float& ox, float& oy) {
    const uint32_t* hrow = hb32 + lane;
    const int N2 = N * 2;
    const float w0 = s_in[node];
    const float w1 = s_in[(size_t)N + node];
    const float w2 = s_in[(size_t)N2 + node];
    const int beg = __builtin_amdgcn_readfirstlane(row_start[node]);
    const int end = __builtin_amdgcn_readfirstlane(row_start[node + 1]);
    float ax = 0.f, ay = 0.f, bx = 0.f, by = 0.f;
    float cx = 0.f, cy = 0.f, dx = 0.f, dy = 0.f;
    for (int e = beg; e < end; e += 8) {
        const int rem = end - e;   // uniform
        uint32_t u[8];
        float w[8];
#pragma unroll
        for (int p = 0; p < 8; p++) {
            int idx = esrc[e + p];                 // uniform addr (pad-covered)
            float ws = (idx < N) ? w0 : ((idx < N2) ? w1 : w2);
            bool act = p < rem;
            w[p] = act ? ws : 0.f;
            idx = act ? idx : 0;
            u[p] = hrow[(size_t)idx * 64];         // 256B row, 8 in flight
        }
#pragma unroll
        for (int p = 0; p < 8; p += 4) {
            ax = fmaf(BF16_LO(u[p]),     w[p],     ax);
            ay = fmaf(BF16_HI(u[p]),     w[p],     ay);
            bx = fmaf(BF16_LO(u[p + 1]), w[p + 1], bx);
            by = fmaf(BF16_HI(u[p + 1]), w[p + 1], by);
            cx = fmaf(BF16_LO(u[p + 2]), w[p + 2], cx);
            cy = fmaf(BF16_HI(u[p + 2]), w[p + 2], cy);
            dx = fmaf(BF16_LO(u[p + 3]), w[p + 3], dx);
            dy = fmaf(BF16_HI(u[p + 3]), w[p + 3], dy);
        }
    }
    ox = (ax + bx) + (cx + dx);
    oy = (ay + by) + (cy + dy);
}

// --- fused gather layer 0: combined CSR + bias + leakyReLU -> acc0 (fp32) --
__global__ __launch_bounds__(256)
void gather_l0(const u16* __restrict__ hb, const int* __restrict__ row_start,
               const int* __restrict__ esrc, const float* __restrict__ s_in,
               const float* __restrict__ b, float* __restrict__ out, int N) {
    int node = blockIdx.x * 4 + (threadIdx.x >> 6);
    if (node >= N) return;
    int lane = threadIdx.x & 63;
    float tx, ty;
    gather_all((const uint32_t*)hb, row_start, esrc, s_in, node, lane, N, tx, ty);
    int c0 = lane * 2;
    tx += b[c0] + b[128 + c0] + b[256 + c0];
    ty += b[c0 + 1] + b[128 + c0 + 1] + b[256 + c0 + 1];
    tx = fmaxf(tx, 0.f) + 0.01f * fminf(tx, 0.f);
    ty = fmaxf(ty, 0.f) + 0.01f * fminf(ty, 0.f);
    *(float2*)(out + (size_t)node * 128 + c0) = make_float2(tx, ty);
}

// --- fused gather layer 1: combined CSR + bias -> out_h; + logits ----------
__global__ __launch_bounds__(256)
void gather_l1(const u16* __restrict__ hb, const int* __restrict__ row_start,
               const int* __restrict__ esrc, const float* __restrict__ s_in,
               const float* __restrict__ b, const float* __restrict__ fcW,
               const float* __restrict__ fcb, float* __restrict__ out_h,
               float* __restrict__ out_logits, int N) {
    int node = blockIdx.x * 4 + (threadIdx.x >> 6);
    if (node >= N) return;
    int lane = threadIdx.x & 63;
    float tx, ty;
    gather_all((const uint32_t*)hb, row_start, esrc, s_in, node, lane, N, tx, ty);
    int c0 = lane * 2;
    tx += b[c0] + b[128 + c0] + b[256 + c0];
    ty += b[c0 + 1] + b[128 + c0 + 1] + b[256 + c0 + 1];
    *(float2*)(out_h + (size_t)node * 128 + c0) = make_float2(tx, ty);

    const float* fc0 = fcW + (size_t)c0 * 16;
    float p[16];
#pragma unroll
    for (int j = 0; j < 16; j++) p[j] = tx * fc0[j] + ty * fc0[16 + j];
#pragma unroll
    for (int off = 1; off < 64; off <<= 1) {
#pragma unroll
        for (int j = 0; j < 16; j++) p[j] += __shfl_xor(p[j], off);
    }
    if (lane == 0) {
        float* lp = out_logits + (size_t)node * 16;
        *(float4*)(lp + 0)  = make_float4(p[0] + fcb[0],  p[1] + fcb[1],  p[2] + fcb[2],  p[3] + fcb[3]);
        *(float4*)(lp + 4)  = make_float4(p[4] + fcb[4],  p[5] + fcb[5],  p[6] + fcb[6],  p[7] + fcb[7]);
        *(float4*)(lp + 8)  = make_float4(p[8] + fcb[8],  p[9] + fcb[9],  p[10] + fcb[10], p[11] + fcb[11]);
        *(float4*)(lp + 12) = make_float4(p[12] + fcb[12], p[13] + fcb[13], p[14] + fcb[14], p[15] + fcb[15]);
    }
}

extern "C" void kernel_launch(void* const* d_in, const int* in_sizes, int n_in,
                              void* d_out, int out_size, void* d_ws, size_t ws_size,
                              hipStream_t stream) {
    const float* x   = (const float*)d_in[0];
    const int*   src = (const int*)d_in[1];
    const int*   dst = (const int*)d_in[2];
    const float* W0  = (const float*)d_in[3];
    const float* b0  = (const float*)d_in[4];
    const float* W1  = (const float*)d_in[5];
    const float* b1  = (const float*)d_in[6];
    const float* fcW = (const float*)d_in[7];
    const float* fcb = (const float*)d_in[8];

    const int N = in_sizes[0] / 256;   // 100000
    const int E = in_sizes[1] / 3;     // 600000
    const int nb = (N + SCAN_BLK - 1) / SCAN_BLK;

    float* out_h      = (float*)d_out;
    float* out_logits = out_h + (size_t)N * 128;

    char* p = (char*)d_ws;
    auto alloc = [&](size_t bytes) -> char* {
        char* q = p;
        p += (bytes + 255) & ~(size_t)255;
        return q;
    };
    float* s_out     = (float*)alloc(3 * (size_t)N * 4);
    float* s_in      = (float*)alloc(3 * (size_t)N * 4);
    int*   cnt8      = (int*)alloc(2 * 8 * 3 * (size_t)N * 4);  // out8 then in8
    int*   cnt_out8  = cnt8;
    int*   cnt_in8   = cnt8 + 8 * 3 * (size_t)N;
    int*   cnt_all   = (int*)alloc((size_t)N * 4);
    int*   row_start = (int*)alloc((size_t)(N + 1) * 4);
    int*   cursor    = (int*)alloc((size_t)N * CUR_PAD * 4);    // 64B per node
    int*   bsums     = (int*)alloc(1024 * 4);
    int*   esrc      = (int*)alloc(3 * (size_t)E * 4 + 256);    // +pad for over-read
    u16*   w0hi      = (u16*)alloc(3 * 256 * 128 * 2);
    u16*   w0lo      = (u16*)alloc(3 * 256 * 128 * 2);
    u16*   w1hi      = (u16*)alloc(3 * 128 * 128 * 2);
    u16*   w1lo      = (u16*)alloc(3 * 128 * 128 * 2);
    u16*   hb        = (u16*)alloc(3 * (size_t)N * 128 * 2);
    float* acc0      = (float*)alloc((size_t)N * 128 * 4);

    hipMemsetAsync(cnt8, 0, 2 * 8 * 3 * (size_t)N * sizeof(int), stream);

    hist_kernel<<<dim3((E + 256 * HIST_K - 1) / (256 * HIST_K), 3), 256, 0, stream>>>(
        src, dst, cnt_out8, cnt_in8, E, N);
    reduce_scales_kernel<<<(N + 255) / 256, 256, 0, stream>>>(
        cnt_out8, cnt_in8, s_out, s_in, cnt_all, N);

    scan1_kernel<<<nb, SCAN_T, 0, stream>>>(cnt_all, row_start, bsums, N);
    scan2_kernel<<<1, 1, 0, stream>>>(bsums, row_start, nb, N);
    scan3_kernel<<<nb, SCAN_T, 0, stream>>>(row_start, bsums, cursor, nb, N);
    bucket_fill_kernel<<<dim3((E + 256 * BF_K - 1) / (256 * BF_K), 3), 256, 0, stream>>>(
        src, dst, cursor, esrc, E, N);

    prep_w_kernel<<<(3 * 256 * 128 + 3 * 128 * 128 + 255) / 256, 256, 0, stream>>>(
        W0, W1, w0hi, w0lo, w1hi, w1lo);

    int gemm_blocks   = (N + 127) / 128;
    int gather_blocks = (N + 3) / 4;

    // Layer 0: x[N,256] -> hb[r][N,128] bf16 -> acc0[N,128] fp32
    gemm_split_bf16<<<dim3(gemm_blocks, 3), 256, 0, stream>>>(
        x, s_out, w0hi, w0lo, hb, N, 256, N);
    gather_l0<<<gather_blocks, 256, 0, stream>>>(hb, row_start, esrc, s_in, b0, acc0, N);

    // Layer 1: acc0[N,128] -> hb[r][N,128] bf16 -> out_h + logits
    gemm_split_bf16<<<dim3(gemm_blocks, 3), 256, 0, stream>>>(
        acc0, s_out, w1hi, w1lo, hb, N, 128, N);
    gather_l1<<<gather_blocks, 256, 0, stream>>>(hb, row_start, esrc, s_in, b1, fcW, fcb,
                                                 out_h, out_logits, N);
}